// Round 15
// baseline (137.189 us; speedup 1.0000x reference)
//
#include <hip/hip_runtime.h>
#include <cmath>

#define S_SEQ 4096
#define HD 1024
#define NG 3072           // 3*H
#define CHR 32            // rows per scan chunk
#define NCH 128           // chunks (CHR*NCH = 4096)
#define NZ 4              // gemm_part K slices

typedef _Float16 half8_t __attribute__((ext_vector_type(8)));
typedef _Float16 half4_t __attribute__((ext_vector_type(4)));
typedef float f32x4_t __attribute__((ext_vector_type(4)));

__device__ __forceinline__ void gload_lds16(const void* g, void* l) {
  __builtin_amdgcn_global_load_lds(
      (const __attribute__((address_space(1))) void*)g,
      (__attribute__((address_space(3))) void*)l, 16, 0, 0);
}

__device__ __forceinline__ float sigmoidf_(float x) {
  return 1.f / (1.f + __expf(-x));
}
__device__ __forceinline__ float tanhf_(float x) {
  return 1.f - 2.f / (__expf(2.f * x) + 1.f);
}

// ---------------- prep: scan_x FIRST (latency chain starts at t=0), then ---
// ---------------- weight conversion sweep (BW-bound, hides the scan) -------
#define SCAN_BLOCKS 128
#define CONV_BLOCKS 7168
__global__ void prep(const float* __restrict__ W1, const float* __restrict__ W2,
                     _Float16* __restrict__ w1h, _Float16* __restrict__ w2h,
                     const float* __restrict__ x, _Float16* __restrict__ A,
                     _Float16* __restrict__ xsum) {
  const int bid = blockIdx.x;
  if (bid < SCAN_BLOCKS) {
    const int c = bid;                        // chunk 0..127
    const int j = threadIdx.x * 4;            // 4 columns per thread
    const int t0 = c * CHR;
    float4 run = make_float4(0.f, 0.f, 0.f, 0.f);
    for (int t = t0; t < t0 + CHR; t += 8) {
      // 8 independent loads in flight (dep only on cheap run update)
      float4 v[8];
#pragma unroll
      for (int u = 0; u < 8; ++u)
        v[u] = *(const float4*)&x[(size_t)(t + u) * HD + j];
#pragma unroll
      for (int u = 0; u < 8; ++u) {
        half4_t hx, hs;
        hx[0] = (_Float16)v[u].x;  hx[1] = (_Float16)v[u].y;
        hx[2] = (_Float16)v[u].z;  hx[3] = (_Float16)v[u].w;
        hs[0] = (_Float16)run.x;   hs[1] = (_Float16)run.y;
        hs[2] = (_Float16)run.z;   hs[3] = (_Float16)run.w;
        *(half4_t*)&A[(size_t)(t + u) * 2048 + j] = hx;
        *(half4_t*)&A[(size_t)(t + u) * 2048 + 1024 + j] = hs;
        run.x += v[u].x; run.y += v[u].y; run.z += v[u].z; run.w += v[u].w;
      }
    }
    half4_t hxs;
    hxs[0] = (_Float16)run.x; hxs[1] = (_Float16)run.y;
    hxs[2] = (_Float16)run.z; hxs[3] = (_Float16)run.w;
    *(half4_t*)&xsum[(size_t)c * HD + j] = hxs;
  } else {
    const int n1 = NG * 2048 / 4;
    int i = (bid - SCAN_BLOCKS) * 256 + threadIdx.x;
    const float* src = (i < n1) ? (W1 + (size_t)i * 4)
                                : (W2 + (size_t)(i - n1) * 4);
    _Float16* dst = (i < n1) ? (w1h + (size_t)i * 4)
                             : (w2h + (size_t)(i - n1) * 4);
    float4 v = *(const float4*)src;
    half4_t h;
    h[0] = (_Float16)v.x; h[1] = (_Float16)v.y;
    h[2] = (_Float16)v.z; h[3] = (_Float16)v.w;
    *(half4_t*)dst = h;
  }
}

// ---------------- exclusive scan over NZ K-split partials + b1 -------------
__global__ void scan_part(const float* __restrict__ praw,
                          const float* __restrict__ b1,
                          float* __restrict__ pout) {
  int j = blockIdx.x * 256 + threadIdx.x;   // 0..3071
  const size_t SP = (size_t)NCH * NG;
  float run = b1[j];
  for (int c = 0; c < NCH; c += 8) {
    float v[8];
#pragma unroll
    for (int u = 0; u < 8; ++u) {
      size_t i0 = (size_t)(c + u) * NG + j;
      v[u] = (praw[i0] + praw[i0 + SP]) + (praw[i0 + 2 * SP] + praw[i0 + 3 * SP]);
    }
#pragma unroll
    for (int u = 0; u < 8; ++u) {
      pout[(size_t)(c + u) * NG + j] = run;
      run += v[u];
    }
  }
}

// ---------------- partGEMM: praw[z] = xsum @ W1b^T over K window z ---------
__global__ __launch_bounds__(256, 2)
void gemm_part(const _Float16* __restrict__ A, const _Float16* __restrict__ B,
               float* __restrict__ C) {
  __shared__ _Float16 As[128 * 32];
  __shared__ _Float16 Bs[128 * 32];

  const int tid = threadIdx.x;
  const int lane = tid & 63;
  const int wid = tid >> 6;
  const int wr = wid >> 1;
  const int wc = wid & 1;

  const int n0 = blockIdx.x * 128;
  const int koff = blockIdx.z * (1024 / NZ);

  const int srow = lane >> 2;
  const int scol = (lane & 3) << 3;

  const _Float16* gA = A + (size_t)(wid * 32 + srow) * 1024 + koff + scol;
  const _Float16* gB = B + (size_t)(n0 + wid * 32 + srow) * 2048 + koff + scol;
  _Float16* lA = As + (wid * 32) * 32;
  _Float16* lB = Bs + (wid * 32) * 32;

  f32x4_t acc[4][4] = {};

  const int fr = lane & 15;
  const int fk = (lane >> 4) << 3;

  for (int kk = 0; kk < 1024 / NZ; kk += 32) {
    gload_lds16(gA + kk,                    lA);
    gload_lds16(gA + kk + (size_t)16*1024,  lA + 16 * 32);
    gload_lds16(gB + kk,                    lB);
    gload_lds16(gB + kk + (size_t)16*2048,  lB + 16 * 32);
    __syncthreads();

    half8_t af[4], bf[4];
#pragma unroll
    for (int m = 0; m < 4; ++m)
      af[m] = *(const half8_t*)&As[(wr * 64 + m * 16 + fr) * 32 + fk];
#pragma unroll
    for (int n = 0; n < 4; ++n)
      bf[n] = *(const half8_t*)&Bs[(wc * 64 + n * 16 + fr) * 32 + fk];
#pragma unroll
    for (int m = 0; m < 4; ++m)
#pragma unroll
      for (int n = 0; n < 4; ++n)
        acc[m][n] = __builtin_amdgcn_mfma_f32_16x16x32_f16(af[m], bf[n],
                                                           acc[m][n], 0, 0, 0);
    __syncthreads();
  }

  float* Cz = C + (size_t)blockIdx.z * NCH * NG;
  const int crow = wr * 64 + ((lane >> 4) << 2);
  const int ccol = n0 + wc * 64 + fr;
#pragma unroll
  for (int m = 0; m < 4; ++m)
#pragma unroll
    for (int n = 0; n < 4; ++n) {
      const int col = ccol + n * 16;
#pragma unroll
      for (int r = 0; r < 4; ++r)
        Cz[(size_t)(crow + m * 16 + r) * NG + col] = acc[m][n][r];
    }
}

// ---------------- triple-buffered counted-vmcnt GEMM -----------------------
// Block tile 128(M) x BN(N), 4 waves, wave tile 64 x BN/2 (NF = BN/32 frags).
// MODE 1: outf[idx] = (acc + bias[col]) * (float)mulh[idx]   (GEMM2, NT store)
// MODE 2: g = acc + part[(row>>5)*NG + col]; gate epilogue   (GEMM1, plain)
// SWZ 1: 1D grid, XCD-aware remap (NBX N-tiles, 4 M-tiles per XCD group)
#define BARX __builtin_amdgcn_s_barrier()
#define PR1 __builtin_amdgcn_s_setprio(1)
#define PR0 __builtin_amdgcn_s_setprio(0)

template <int NTILE, int MODE, int SWZ, int NBX, int BN>
__global__ __launch_bounds__(256, BN == 192 ? 2 : 3)
void gemm_t3(const _Float16* __restrict__ A, const _Float16* __restrict__ B,
             int N,
             const float* __restrict__ part, _Float16* __restrict__ igb,
             float* __restrict__ outf, _Float16* __restrict__ th,
             const float* __restrict__ bias, const _Float16* __restrict__ mulh) {
  constexpr int KS = NTILE * 32;
  constexpr int NF = BN / 32;          // B frags per wave
  constexpr int NLB = BN / 64;         // B gloads per thread per body
  __shared__ __align__(16) _Float16 sA[3][128 * 32];
  __shared__ __align__(16) _Float16 sB[3][BN * 32];

  const int tid = threadIdx.x;
  const int l = tid & 63;
  const int wid = tid >> 6;
  const int wr = wid >> 1;             // M half (64 rows)
  const int wc = wid & 1;              // N half (BN/2 cols)

  int bx, by;
  if constexpr (SWZ) {
    const int bid = blockIdx.x;
    const int xcd = bid & 7;
    const int q = bid >> 3;
    by = xcd * 4 + q / NBX;
    bx = q % NBX;
  } else {
    bx = blockIdx.x;
    by = blockIdx.y;
  }
  const int m0 = by * 128;
  const int n0 = bx * BN;

  const int srow = tid >> 2;
  const int schunk = (tid & 3) ^ ((tid >> 3) & 3);
  const _Float16* gA = A + (size_t)(m0 + srow) * KS + schunk * 8;
  const _Float16* gB = B + (size_t)(n0 + srow) * KS + schunk * 8;
  const int ldst = tid * 8;

#define STG(bn, kt) do {                                              \
    const int kk_ = (kt) * 32;                                        \
    gload_lds16(gA + kk_,           &sA[bn][ldst]);                   \
    gload_lds16(gA + kk_ + 64 * KS, &sA[bn][2048 + ldst]);            \
    _Pragma("unroll")                                                 \
    for (int jj = 0; jj < NLB; ++jj)                                  \
      gload_lds16(gB + kk_ + jj * 64 * KS, &sB[bn][jj * 2048 + ldst]);\
  } while (0)

#define VMW do {                                                      \
    if constexpr (NLB == 1)                                           \
      asm volatile("s_waitcnt vmcnt(3)" ::: "memory");                \
    else if constexpr (NLB == 2)                                      \
      asm volatile("s_waitcnt vmcnt(4)" ::: "memory");                \
    else                                                              \
      asm volatile("s_waitcnt vmcnt(5)" ::: "memory");                \
  } while (0)

  const int fr = l & 15;
  const int kidx = (((l >> 4) ^ ((l >> 1) & 3)) << 3);
  const int noff = wc * (BN / 2);

  f32x4_t acc[4][NF] = {};

#define BODY(kt, bc, bn) do {                                         \
    int ks_ = (kt) + 2; if (ks_ > NTILE - 1) ks_ = NTILE - 1;         \
    STG(bn, ks_);                                                     \
    half8_t af[4], bf[NF];                                            \
    _Pragma("unroll")                                                 \
    for (int m = 0; m < 4; ++m)                                       \
      af[m] = *(const half8_t*)&sA[bc][(wr*64 + m*16 + fr)*32 + kidx];\
    _Pragma("unroll")                                                 \
    for (int n = 0; n < NF; ++n)                                      \
      bf[n] = *(const half8_t*)&sB[bc][(noff + n*16 + fr)*32 + kidx]; \
    PR1;                                                              \
    _Pragma("unroll")                                                 \
    for (int m = 0; m < 4; ++m)                                       \
      _Pragma("unroll")                                               \
      for (int n = 0; n < NF; ++n)                                    \
        acc[m][n] = __builtin_amdgcn_mfma_f32_16x16x32_f16(           \
            af[m], bf[n], acc[m][n], 0, 0, 0);                        \
    PR0;                                                              \
    VMW; BARX;                                                        \
  } while (0)

  STG(0, 0);
  STG(1, 1);
  VMW; BARX;

#pragma unroll 1
  for (int t3 = 0; t3 < NTILE / 3; ++t3) {
    const int kt = t3 * 3;
    BODY(kt,     0, 2);
    BODY(kt + 1, 1, 0);
    BODY(kt + 2, 2, 1);
  }
  if constexpr (NTILE % 3 >= 1) BODY(NTILE - NTILE % 3,     0, 2);
  if constexpr (NTILE % 3 >= 2) BODY(NTILE - NTILE % 3 + 1, 1, 0);

  // ---- epilogue ----
  const int crow = m0 + wr * 64 + ((l >> 4) << 2);
  const int ccol = n0 + noff + fr;

  float pv[2][NF];
  if constexpr (MODE == 2) {
    const int cbase = crow >> 5;   // lane-uniform per 64-row wave span
#pragma unroll
    for (int h = 0; h < 2; ++h)
#pragma unroll
      for (int n = 0; n < NF; ++n)
        pv[h][n] = part[(size_t)(cbase + h) * NG + ccol + n * 16];
  }

#pragma unroll
  for (int m = 0; m < 4; ++m)
#pragma unroll
    for (int n = 0; n < NF; ++n) {
      const int col = ccol + n * 16;
#pragma unroll
      for (int r = 0; r < 4; ++r) {
        const int row = crow + m * 16 + r;
        const float v = acc[m][n][r];
        if (MODE == 1) {
          size_t idx = (size_t)row * N + col;
          // NT store helps here: keeps 16MB of dead writes out of L2,
          // protecting th/igb/w2h read set (R14 A/B: rest −4.5 µs)
          __builtin_nontemporal_store((v + bias[col]) * (float)mulh[idx],
                                      &outf[idx]);
        } else {
          float g = v + pv[m >> 1][n];
          if (col < 1024)
            igb[(size_t)row * HD + col] = (_Float16)sigmoidf_(g);
          else if (col < 2048)
            // plain store: NT here slowed GEMM1 by ~4.5 µs (R14 A/B)
            outf[(size_t)row * HD + (col - 1024)] = sigmoidf_(g);
          else
            th[(size_t)row * HD + (col - 2048)] = (_Float16)tanhf_(g);
        }
      }
    }
#undef STG
#undef VMW
#undef BODY
}

// ---------------- launch ----------------
extern "C" void kernel_launch(void* const* d_in, const int* in_sizes, int n_in,
                              void* d_out, int out_size, void* d_ws, size_t ws_size,
                              hipStream_t stream) {
  const float* x  = (const float*)d_in[0];
  const float* W1 = (const float*)d_in[1];
  const float* b1 = (const float*)d_in[2];
  const float* W2 = (const float*)d_in[3];
  const float* b2 = (const float*)d_in[4];
  float* out0 = (float*)d_out;                          // fg [4096][1024]
  float* out1 = out0 + (size_t)S_SEQ * HD;              // hr [4096][1024]

  char* ws = (char*)d_ws;
  _Float16* Ah    = (_Float16*)(ws);                        // 16 MiB [4096][2048]
  _Float16* w1h   = (_Float16*)(ws + ((size_t)16 << 20));   // 12 MiB [3072][2048]
  _Float16* w2h   = (_Float16*)(ws + ((size_t)28 << 20));   //  2 MiB [1024][1024]
  _Float16* xsumh = (_Float16*)(ws + ((size_t)30 << 20));   // .25MiB [128][1024]
  float*    praw  = (float*)   (ws + ((size_t)31 << 20));   //  6 MiB [4][128][3072]
  float*    pout  = (float*)   (ws + ((size_t)37 << 20));   // 1.5MiB [128][3072]
  _Float16* igb   = (_Float16*)(ws + ((size_t)39 << 20));   //  8 MiB [4096][1024]
  _Float16* th    = (_Float16*)(ws + ((size_t)47 << 20));   //  8 MiB [4096][1024]

  prep<<<dim3(SCAN_BLOCKS + CONV_BLOCKS), dim3(256), 0, stream>>>(
      W1, W2, w1h, w2h, x, Ah, xsumh);

  gemm_part<<<dim3(NG / 128, 1, NZ), dim3(256), 0, stream>>>(
      xsumh, w1h + 1024, praw);

  scan_part<<<dim3(NG / 256), dim3(256), 0, stream>>>(praw, b1, pout);

  // GEMM1: 128x192 tile, 512 blocks = exactly 2/CU, XCD-swizzled
  gemm_t3<64, 2, 1, NG / 192, 192><<<dim3(512), dim3(256), 0, stream>>>(
      Ah, w1h, NG, pout, igb, out0, th, nullptr, nullptr);

  // GEMM2: 128x64 tile -> 512 blocks = 2/CU, XCD-swizzled
  gemm_t3<32, 1, 1, 16, 64><<<dim3(512), dim3(256), 0, stream>>>(
      th, w2h, HD, nullptr, nullptr, out1, nullptr, b2, igb);
}

// Round 17
// 127.156 us; speedup vs baseline: 1.0789x; 1.0789x over previous
//
#include <hip/hip_runtime.h>
#include <cmath>

#define S_SEQ 4096
#define HD 1024
#define NG 3072           // 3*H
#define CHR 32            // rows per scan chunk
#define NCH 128           // chunks (CHR*NCH = 4096)
#define NZ 4              // gemm_part K slices

typedef _Float16 half8_t __attribute__((ext_vector_type(8)));
typedef _Float16 half4_t __attribute__((ext_vector_type(4)));
typedef float f32x4_t __attribute__((ext_vector_type(4)));

__device__ __forceinline__ void gload_lds16(const void* g, void* l) {
  __builtin_amdgcn_global_load_lds(
      (const __attribute__((address_space(1))) void*)g,
      (__attribute__((address_space(3))) void*)l, 16, 0, 0);
}

__device__ __forceinline__ float sigmoidf_(float x) {
  return 1.f / (1.f + __expf(-x));
}
__device__ __forceinline__ float tanhf_(float x) {
  return 1.f - 2.f / (__expf(2.f * x) + 1.f);
}

// ---------------- prep: scan_x FIRST, then weight conversion sweep ---------
#define SCAN_BLOCKS 128
#define CONV_BLOCKS 7168
__global__ void prep(const float* __restrict__ W1, const float* __restrict__ W2,
                     _Float16* __restrict__ w1h, _Float16* __restrict__ w2h,
                     const float* __restrict__ x, _Float16* __restrict__ A,
                     _Float16* __restrict__ xsum) {
  const int bid = blockIdx.x;
  if (bid < SCAN_BLOCKS) {
    const int c = bid;                        // chunk 0..127
    const int j = threadIdx.x * 4;            // 4 columns per thread
    const int t0 = c * CHR;
    float4 run = make_float4(0.f, 0.f, 0.f, 0.f);
    for (int t = t0; t < t0 + CHR; t += 8) {
      float4 v[8];
#pragma unroll
      for (int u = 0; u < 8; ++u)
        v[u] = *(const float4*)&x[(size_t)(t + u) * HD + j];
#pragma unroll
      for (int u = 0; u < 8; ++u) {
        half4_t hx, hs;
        hx[0] = (_Float16)v[u].x;  hx[1] = (_Float16)v[u].y;
        hx[2] = (_Float16)v[u].z;  hx[3] = (_Float16)v[u].w;
        hs[0] = (_Float16)run.x;   hs[1] = (_Float16)run.y;
        hs[2] = (_Float16)run.z;   hs[3] = (_Float16)run.w;
        *(half4_t*)&A[(size_t)(t + u) * 2048 + j] = hx;
        *(half4_t*)&A[(size_t)(t + u) * 2048 + 1024 + j] = hs;
        run.x += v[u].x; run.y += v[u].y; run.z += v[u].z; run.w += v[u].w;
      }
    }
    half4_t hxs;
    hxs[0] = (_Float16)run.x; hxs[1] = (_Float16)run.y;
    hxs[2] = (_Float16)run.z; hxs[3] = (_Float16)run.w;
    *(half4_t*)&xsum[(size_t)c * HD + j] = hxs;
  } else {
    const int n1 = NG * 2048 / 4;
    int i = (bid - SCAN_BLOCKS) * 256 + threadIdx.x;
    const float* src = (i < n1) ? (W1 + (size_t)i * 4)
                                : (W2 + (size_t)(i - n1) * 4);
    _Float16* dst = (i < n1) ? (w1h + (size_t)i * 4)
                             : (w2h + (size_t)(i - n1) * 4);
    float4 v = *(const float4*)src;
    half4_t h;
    h[0] = (_Float16)v.x; h[1] = (_Float16)v.y;
    h[2] = (_Float16)v.z; h[3] = (_Float16)v.w;
    *(half4_t*)dst = h;
  }
}

// ---------------- exclusive scan over NZ K-split partials + b1 -------------
__global__ void scan_part(const float* __restrict__ praw,
                          const float* __restrict__ b1,
                          float* __restrict__ pout) {
  int j = blockIdx.x * 256 + threadIdx.x;   // 0..3071
  const size_t SP = (size_t)NCH * NG;
  float run = b1[j];
  for (int c = 0; c < NCH; c += 8) {
    float v[8];
#pragma unroll
    for (int u = 0; u < 8; ++u) {
      size_t i0 = (size_t)(c + u) * NG + j;
      v[u] = (praw[i0] + praw[i0 + SP]) + (praw[i0 + 2 * SP] + praw[i0 + 3 * SP]);
    }
#pragma unroll
    for (int u = 0; u < 8; ++u) {
      pout[(size_t)(c + u) * NG + j] = run;
      run += v[u];
    }
  }
}

// ---------------- partGEMM: praw[z] = xsum @ W1b^T over K window z ---------
__global__ __launch_bounds__(256, 2)
void gemm_part(const _Float16* __restrict__ A, const _Float16* __restrict__ B,
               float* __restrict__ C) {
  __shared__ _Float16 As[128 * 32];
  __shared__ _Float16 Bs[128 * 32];

  const int tid = threadIdx.x;
  const int lane = tid & 63;
  const int wid = tid >> 6;
  const int wr = wid >> 1;
  const int wc = wid & 1;

  const int n0 = blockIdx.x * 128;
  const int koff = blockIdx.z * (1024 / NZ);

  const int srow = lane >> 2;
  const int scol = (lane & 3) << 3;

  const _Float16* gA = A + (size_t)(wid * 32 + srow) * 1024 + koff + scol;
  const _Float16* gB = B + (size_t)(n0 + wid * 32 + srow) * 2048 + koff + scol;
  _Float16* lA = As + (wid * 32) * 32;
  _Float16* lB = Bs + (wid * 32) * 32;

  f32x4_t acc[4][4] = {};

  const int fr = lane & 15;
  const int fk = (lane >> 4) << 3;

  for (int kk = 0; kk < 1024 / NZ; kk += 32) {
    gload_lds16(gA + kk,                    lA);
    gload_lds16(gA + kk + (size_t)16*1024,  lA + 16 * 32);
    gload_lds16(gB + kk,                    lB);
    gload_lds16(gB + kk + (size_t)16*2048,  lB + 16 * 32);
    __syncthreads();

    half8_t af[4], bf[4];
#pragma unroll
    for (int m = 0; m < 4; ++m)
      af[m] = *(const half8_t*)&As[(wr * 64 + m * 16 + fr) * 32 + fk];
#pragma unroll
    for (int n = 0; n < 4; ++n)
      bf[n] = *(const half8_t*)&Bs[(wc * 64 + n * 16 + fr) * 32 + fk];
#pragma unroll
    for (int m = 0; m < 4; ++m)
#pragma unroll
      for (int n = 0; n < 4; ++n)
        acc[m][n] = __builtin_amdgcn_mfma_f32_16x16x32_f16(af[m], bf[n],
                                                           acc[m][n], 0, 0, 0);
    __syncthreads();
  }

  float* Cz = C + (size_t)blockIdx.z * NCH * NG;
  const int crow = wr * 64 + ((lane >> 4) << 2);
  const int ccol = n0 + wc * 64 + fr;
#pragma unroll
  for (int m = 0; m < 4; ++m)
#pragma unroll
    for (int n = 0; n < 4; ++n) {
      const int col = ccol + n * 16;
#pragma unroll
      for (int r = 0; r < 4; ++r)
        Cz[(size_t)(crow + m * 16 + r) * NG + col] = acc[m][n][r];
    }
}

#define BARX __builtin_amdgcn_s_barrier()
#define PR1 __builtin_amdgcn_s_setprio(1)
#define PR0 __builtin_amdgcn_s_setprio(0)

// ---------------- GEMM1: 128x192 tile, BK=64 double-buffer -----------------
// Wave tile 64x96 -> acc[4][6] (6 N-frags of 16 — R16 bug was [4][3]).
// Half the vmcnt+barrier events of BK=32; same occupancy (2/CU, 80KB LDS).
// LDS chunk-XOR swizzle: LDS[r][c] holds G[r][c^(r&7)] (16B chunks, 8/row).
__global__ __launch_bounds__(256, 2)
void gemm1_k64(const _Float16* __restrict__ A, const _Float16* __restrict__ B,
               const float* __restrict__ part, _Float16* __restrict__ igb,
               float* __restrict__ out0, _Float16* __restrict__ th) {
  constexpr int KS = 2048;
  constexpr int NT = 32;               // K-tiles of 64
  __shared__ __align__(16) _Float16 sA[2][128 * 64];
  __shared__ __align__(16) _Float16 sB[2][192 * 64];

  const int tid = threadIdx.x;
  const int l = tid & 63;
  const int wid = tid >> 6;
  const int wr = wid >> 1;             // M half (64 rows)
  const int wc = wid & 1;              // N half (96 cols)

  // bijective XCD swizzle: 512 blocks = 8 XCD x 4 M-tiles x 16 N-tiles
  const int bid = blockIdx.x;
  const int xcd = bid & 7;
  const int q = bid >> 3;
  const int by = xcd * 4 + q / 16;
  const int bx = q % 16;
  const int m0 = by * 128;
  const int n0 = bx * 192;

  // staging: thread -> rows rB+32j, chunk cB; source chunk pre-XORed
  const int rB = tid >> 3;             // 0..31
  const int cB = tid & 7;
  const int csw = (cB ^ (rB & 7)) << 3;      // halfs
  const _Float16* gA0 = A + (size_t)(m0 + rB) * KS + csw;
  const _Float16* gB0 = B + (size_t)(n0 + rB) * KS + csw;
  const int dsto = rB * 64 + cB * 8;

#define STG(bb, kt) do {                                               \
    const int kk_ = (kt) * 64;                                         \
    _Pragma("unroll")                                                  \
    for (int j = 0; j < 4; ++j)                                        \
      gload_lds16(gA0 + (size_t)(32 * j) * KS + kk_,                   \
                  (_Float16*)&sA[bb][dsto + j * 2048]);                \
    _Pragma("unroll")                                                  \
    for (int j = 0; j < 6; ++j)                                        \
      gload_lds16(gB0 + (size_t)(32 * j) * KS + kk_,                   \
                  (_Float16*)&sB[bb][dsto + j * 2048]);                \
  } while (0)

  const int fr = l & 15;
  const int kq = l >> 4;               // 0..3 : k-chunk within 32-half

  // element (row, h*32 + kq*8 .. +7) at halfs row*64 + ((h*4+kq)^(row&7))*8
#define RDA(dst, M, H, bb) do {                                        \
    const int row_ = wr * 64 + (M) * 16 + fr;                          \
    dst = *(const half8_t*)&sA[bb][row_ * 64 +                         \
          ((((H) * 4 + kq) ^ (row_ & 7)) << 3)];                       \
  } while (0)
#define RDB(dst, N_, H, bb) do {                                       \
    const int row_ = wc * 96 + (N_) * 16 + fr;                         \
    dst = *(const half8_t*)&sB[bb][row_ * 64 +                         \
          ((((H) * 4 + kq) ^ (row_ & 7)) << 3)];                       \
  } while (0)

  f32x4_t acc[4][6] = {};

#define BODY(t, bb) do {                                               \
    const int nt_ = ((t) + 1 < NT) ? (t) + 1 : NT - 1;                 \
    STG((bb) ^ 1, nt_);                                                \
    half8_t af[4][2], bf[6][2];                                        \
    _Pragma("unroll")                                                  \
    for (int m = 0; m < 4; ++m) {                                      \
      RDA(af[m][0], m, 0, bb); RDA(af[m][1], m, 1, bb);                \
    }                                                                  \
    _Pragma("unroll")                                                  \
    for (int n = 0; n < 6; ++n) {                                      \
      RDB(bf[n][0], n, 0, bb); RDB(bf[n][1], n, 1, bb);                \
    }                                                                  \
    PR1;                                                               \
    _Pragma("unroll")                                                  \
    for (int m = 0; m < 4; ++m)                                        \
      _Pragma("unroll")                                                \
      for (int n = 0; n < 6; ++n) {                                    \
        acc[m][n] = __builtin_amdgcn_mfma_f32_16x16x32_f16(            \
            af[m][0], bf[n][0], acc[m][n], 0, 0, 0);                   \
        acc[m][n] = __builtin_amdgcn_mfma_f32_16x16x32_f16(            \
            af[m][1], bf[n][1], acc[m][n], 0, 0, 0);                   \
      }                                                                \
    PR0;                                                               \
    asm volatile("s_waitcnt vmcnt(0)" ::: "memory");                   \
    BARX;                                                              \
  } while (0)

  STG(0, 0);
  asm volatile("s_waitcnt vmcnt(0)" ::: "memory");
  BARX;

#pragma unroll 1
  for (int t2 = 0; t2 < NT / 2; ++t2) {
    BODY(2 * t2,     0);
    BODY(2 * t2 + 1, 1);
  }

  // ---- epilogue: gate activations ----
  const int crow = m0 + wr * 64 + ((l >> 4) << 2);
  const int ccol = n0 + wc * 96 + fr;

  float pv[2][6];
  const int cbase = crow >> 5;   // lane-uniform per 64-row wave span
#pragma unroll
  for (int h = 0; h < 2; ++h)
#pragma unroll
    for (int n = 0; n < 6; ++n)
      pv[h][n] = part[(size_t)(cbase + h) * NG + ccol + n * 16];

#pragma unroll
  for (int m = 0; m < 4; ++m)
#pragma unroll
    for (int n = 0; n < 6; ++n) {
      const int col = ccol + n * 16;
#pragma unroll
      for (int r = 0; r < 4; ++r) {
        const int row = crow + m * 16 + r;
        float g = acc[m][n][r] + pv[m >> 1][n];
        if (col < 1024)
          igb[(size_t)row * HD + col] = (_Float16)sigmoidf_(g);
        else if (col < 2048)
          out0[(size_t)row * HD + (col - 1024)] = sigmoidf_(g);
        else
          th[(size_t)row * HD + (col - 2048)] = (_Float16)tanhf_(g);
      }
    }
#undef STG
#undef RDA
#undef RDB
#undef BODY
}

// ---------------- triple-buffered counted-vmcnt GEMM (GEMM2) ---------------
template <int NTILE, int SWZ, int NBX, int BN>
__global__ __launch_bounds__(256, 3)
void gemm_t3(const _Float16* __restrict__ A, const _Float16* __restrict__ B,
             int N, float* __restrict__ outf,
             const float* __restrict__ bias, const _Float16* __restrict__ mulh) {
  constexpr int KS = NTILE * 32;
  constexpr int NF = BN / 32;
  constexpr int NLB = BN / 64;
  __shared__ __align__(16) _Float16 sA[3][128 * 32];
  __shared__ __align__(16) _Float16 sB[3][BN * 32];

  const int tid = threadIdx.x;
  const int l = tid & 63;
  const int wid = tid >> 6;
  const int wr = wid >> 1;
  const int wc = wid & 1;

  int bx, by;
  if constexpr (SWZ) {
    const int bid = blockIdx.x;
    const int xcd = bid & 7;
    const int q = bid >> 3;
    by = xcd * 4 + q / NBX;
    bx = q % NBX;
  } else {
    bx = blockIdx.x;
    by = blockIdx.y;
  }
  const int m0 = by * 128;
  const int n0 = bx * BN;

  const int srow = tid >> 2;
  const int schunk = (tid & 3) ^ ((tid >> 3) & 3);
  const _Float16* gA = A + (size_t)(m0 + srow) * KS + schunk * 8;
  const _Float16* gB = B + (size_t)(n0 + srow) * KS + schunk * 8;
  const int ldst = tid * 8;

#define STG(bn, kt) do {                                              \
    const int kk_ = (kt) * 32;                                        \
    gload_lds16(gA + kk_,           &sA[bn][ldst]);                   \
    gload_lds16(gA + kk_ + 64 * KS, &sA[bn][2048 + ldst]);            \
    _Pragma("unroll")                                                 \
    for (int jj = 0; jj < NLB; ++jj)                                  \
      gload_lds16(gB + kk_ + jj * 64 * KS, &sB[bn][jj * 2048 + ldst]);\
  } while (0)

#define VMW do {                                                      \
    if constexpr (NLB == 1)                                           \
      asm volatile("s_waitcnt vmcnt(3)" ::: "memory");                \
    else                                                              \
      asm volatile("s_waitcnt vmcnt(4)" ::: "memory");                \
  } while (0)

  const int fr = l & 15;
  const int kidx = (((l >> 4) ^ ((l >> 1) & 3)) << 3);
  const int noff = wc * (BN / 2);

  f32x4_t acc[4][NF] = {};

#define BODY(kt, bc, bn) do {                                         \
    int ks_ = (kt) + 2; if (ks_ > NTILE - 1) ks_ = NTILE - 1;         \
    STG(bn, ks_);                                                     \
    half8_t af[4], bf[NF];                                            \
    _Pragma("unroll")                                                 \
    for (int m = 0; m < 4; ++m)                                       \
      af[m] = *(const half8_t*)&sA[bc][(wr*64 + m*16 + fr)*32 + kidx];\
    _Pragma("unroll")                                                 \
    for (int n = 0; n < NF; ++n)                                      \
      bf[n] = *(const half8_t*)&sB[bc][(noff + n*16 + fr)*32 + kidx]; \
    PR1;                                                              \
    _Pragma("unroll")                                                 \
    for (int m = 0; m < 4; ++m)                                       \
      _Pragma("unroll")                                               \
      for (int n = 0; n < NF; ++n)                                    \
        acc[m][n] = __builtin_amdgcn_mfma_f32_16x16x32_f16(           \
            af[m], bf[n], acc[m][n], 0, 0, 0);                        \
    PR0;                                                              \
    VMW; BARX;                                                        \
  } while (0)

  STG(0, 0);
  STG(1, 1);
  VMW; BARX;

#pragma unroll 1
  for (int t3 = 0; t3 < NTILE / 3; ++t3) {
    const int kt = t3 * 3;
    BODY(kt,     0, 2);
    BODY(kt + 1, 1, 0);
    BODY(kt + 2, 2, 1);
  }
  if constexpr (NTILE % 3 >= 1) BODY(NTILE - NTILE % 3,     0, 2);
  if constexpr (NTILE % 3 >= 2) BODY(NTILE - NTILE % 3 + 1, 1, 0);

  const int crow = m0 + wr * 64 + ((l >> 4) << 2);
  const int ccol = n0 + noff + fr;
#pragma unroll
  for (int m = 0; m < 4; ++m)
#pragma unroll
    for (int n = 0; n < NF; ++n) {
      const int col = ccol + n * 16;
#pragma unroll
      for (int r = 0; r < 4; ++r) {
        const int row = crow + m * 16 + r;
        size_t idx = (size_t)row * N + col;
        outf[idx] = (acc[m][n][r] + bias[col]) * (float)mulh[idx];
      }
    }
#undef STG
#undef VMW
#undef BODY
}

// ---------------- launch ----------------
extern "C" void kernel_launch(void* const* d_in, const int* in_sizes, int n_in,
                              void* d_out, int out_size, void* d_ws, size_t ws_size,
                              hipStream_t stream) {
  const float* x  = (const float*)d_in[0];
  const float* W1 = (const float*)d_in[1];
  const float* b1 = (const float*)d_in[2];
  const float* W2 = (const float*)d_in[3];
  const float* b2 = (const float*)d_in[4];
  float* out0 = (float*)d_out;                          // fg [4096][1024]
  float* out1 = out0 + (size_t)S_SEQ * HD;              // hr [4096][1024]

  char* ws = (char*)d_ws;
  _Float16* Ah    = (_Float16*)(ws);                        // 16 MiB [4096][2048]
  _Float16* w1h   = (_Float16*)(ws + ((size_t)16 << 20));   // 12 MiB [3072][2048]
  _Float16* w2h   = (_Float16*)(ws + ((size_t)28 << 20));   //  2 MiB [1024][1024]
  _Float16* xsumh = (_Float16*)(ws + ((size_t)30 << 20));   // .25MiB [128][1024]
  float*    praw  = (float*)   (ws + ((size_t)31 << 20));   //  6 MiB [4][128][3072]
  float*    pout  = (float*)   (ws + ((size_t)37 << 20));   // 1.5MiB [128][3072]
  _Float16* igb   = (_Float16*)(ws + ((size_t)39 << 20));   //  8 MiB [4096][1024]
  _Float16* th    = (_Float16*)(ws + ((size_t)47 << 20));   //  8 MiB [4096][1024]

  prep<<<dim3(SCAN_BLOCKS + CONV_BLOCKS), dim3(256), 0, stream>>>(
      W1, W2, w1h, w2h, x, Ah, xsumh);

  gemm_part<<<dim3(NG / 128, 1, NZ), dim3(256), 0, stream>>>(
      xsumh, w1h + 1024, praw);

  scan_part<<<dim3(NG / 256), dim3(256), 0, stream>>>(praw, b1, pout);

  // GEMM1: 128x192, BK=64 dbuf, 512 blocks = 2/CU, XCD-swizzled
  gemm1_k64<<<dim3(512), dim3(256), 0, stream>>>(
      Ah, w1h, pout, igb, out0, th);

  // GEMM2: 128x64 tile -> 512 blocks = 2/CU, XCD-swizzled (R12 config)
  gemm_t3<32, 1, 16, 64><<<dim3(512), dim3(256), 0, stream>>>(
      th, w2h, HD, out1, b2, igb);
}

// Round 18
// 123.237 us; speedup vs baseline: 1.1132x; 1.0318x over previous
//
#include <hip/hip_runtime.h>
#include <cmath>

#define S_SEQ 4096
#define HD 1024
#define NG 3072           // 3*H
#define CHR 32            // rows per scan chunk
#define NCH 128           // chunks (CHR*NCH = 4096)
#define NZ 4              // gemm_part K slices

typedef _Float16 half8_t __attribute__((ext_vector_type(8)));
typedef _Float16 half4_t __attribute__((ext_vector_type(4)));
typedef float f32x4_t __attribute__((ext_vector_type(4)));

__device__ __forceinline__ void gload_lds16(const void* g, void* l) {
  __builtin_amdgcn_global_load_lds(
      (const __attribute__((address_space(1))) void*)g,
      (__attribute__((address_space(3))) void*)l, 16, 0, 0);
}

__device__ __forceinline__ float sigmoidf_(float x) {
  return 1.f / (1.f + __expf(-x));
}
__device__ __forceinline__ float tanhf_(float x) {
  return 1.f - 2.f / (__expf(2.f * x) + 1.f);
}

// ---------------- prep: scan_x FIRST, then weight conversion sweep ---------
#define SCAN_BLOCKS 128
#define CONV_BLOCKS 7168
__global__ void prep(const float* __restrict__ W1, const float* __restrict__ W2,
                     _Float16* __restrict__ w1h, _Float16* __restrict__ w2h,
                     const float* __restrict__ x, _Float16* __restrict__ A,
                     _Float16* __restrict__ xsum) {
  const int bid = blockIdx.x;
  if (bid < SCAN_BLOCKS) {
    const int c = bid;                        // chunk 0..127
    const int j = threadIdx.x * 4;            // 4 columns per thread
    const int t0 = c * CHR;
    float4 run = make_float4(0.f, 0.f, 0.f, 0.f);
    for (int t = t0; t < t0 + CHR; t += 8) {
      float4 v[8];
#pragma unroll
      for (int u = 0; u < 8; ++u)
        v[u] = *(const float4*)&x[(size_t)(t + u) * HD + j];
#pragma unroll
      for (int u = 0; u < 8; ++u) {
        half4_t hx, hs;
        hx[0] = (_Float16)v[u].x;  hx[1] = (_Float16)v[u].y;
        hx[2] = (_Float16)v[u].z;  hx[3] = (_Float16)v[u].w;
        hs[0] = (_Float16)run.x;   hs[1] = (_Float16)run.y;
        hs[2] = (_Float16)run.z;   hs[3] = (_Float16)run.w;
        *(half4_t*)&A[(size_t)(t + u) * 2048 + j] = hx;
        *(half4_t*)&A[(size_t)(t + u) * 2048 + 1024 + j] = hs;
        run.x += v[u].x; run.y += v[u].y; run.z += v[u].z; run.w += v[u].w;
      }
    }
    half4_t hxs;
    hxs[0] = (_Float16)run.x; hxs[1] = (_Float16)run.y;
    hxs[2] = (_Float16)run.z; hxs[3] = (_Float16)run.w;
    *(half4_t*)&xsum[(size_t)c * HD + j] = hxs;
  } else {
    const int n1 = NG * 2048 / 4;
    int i = (bid - SCAN_BLOCKS) * 256 + threadIdx.x;
    const float* src = (i < n1) ? (W1 + (size_t)i * 4)
                                : (W2 + (size_t)(i - n1) * 4);
    _Float16* dst = (i < n1) ? (w1h + (size_t)i * 4)
                             : (w2h + (size_t)(i - n1) * 4);
    float4 v = *(const float4*)src;
    half4_t h;
    h[0] = (_Float16)v.x; h[1] = (_Float16)v.y;
    h[2] = (_Float16)v.z; h[3] = (_Float16)v.w;
    *(half4_t*)dst = h;
  }
}

// ---------------- exclusive scan over NZ K-split partials + b1 -------------
__global__ void scan_part(const float* __restrict__ praw,
                          const float* __restrict__ b1,
                          float* __restrict__ pout) {
  int j = blockIdx.x * 256 + threadIdx.x;   // 0..3071
  const size_t SP = (size_t)NCH * NG;
  float run = b1[j];
  for (int c = 0; c < NCH; c += 8) {
    float v[8];
#pragma unroll
    for (int u = 0; u < 8; ++u) {
      size_t i0 = (size_t)(c + u) * NG + j;
      v[u] = (praw[i0] + praw[i0 + SP]) + (praw[i0 + 2 * SP] + praw[i0 + 3 * SP]);
    }
#pragma unroll
    for (int u = 0; u < 8; ++u) {
      pout[(size_t)(c + u) * NG + j] = run;
      run += v[u];
    }
  }
}

// ---------------- partGEMM: praw[z] = xsum @ W1b^T over K window z ---------
__global__ __launch_bounds__(256, 2)
void gemm_part(const _Float16* __restrict__ A, const _Float16* __restrict__ B,
               float* __restrict__ C) {
  __shared__ _Float16 As[128 * 32];
  __shared__ _Float16 Bs[128 * 32];

  const int tid = threadIdx.x;
  const int lane = tid & 63;
  const int wid = tid >> 6;
  const int wr = wid >> 1;
  const int wc = wid & 1;

  const int n0 = blockIdx.x * 128;
  const int koff = blockIdx.z * (1024 / NZ);

  const int srow = lane >> 2;
  const int scol = (lane & 3) << 3;

  const _Float16* gA = A + (size_t)(wid * 32 + srow) * 1024 + koff + scol;
  const _Float16* gB = B + (size_t)(n0 + wid * 32 + srow) * 2048 + koff + scol;
  _Float16* lA = As + (wid * 32) * 32;
  _Float16* lB = Bs + (wid * 32) * 32;

  f32x4_t acc[4][4] = {};

  const int fr = lane & 15;
  const int fk = (lane >> 4) << 3;

  for (int kk = 0; kk < 1024 / NZ; kk += 32) {
    gload_lds16(gA + kk,                    lA);
    gload_lds16(gA + kk + (size_t)16*1024,  lA + 16 * 32);
    gload_lds16(gB + kk,                    lB);
    gload_lds16(gB + kk + (size_t)16*2048,  lB + 16 * 32);
    __syncthreads();

    half8_t af[4], bf[4];
#pragma unroll
    for (int m = 0; m < 4; ++m)
      af[m] = *(const half8_t*)&As[(wr * 64 + m * 16 + fr) * 32 + fk];
#pragma unroll
    for (int n = 0; n < 4; ++n)
      bf[n] = *(const half8_t*)&Bs[(wc * 64 + n * 16 + fr) * 32 + fk];
#pragma unroll
    for (int m = 0; m < 4; ++m)
#pragma unroll
      for (int n = 0; n < 4; ++n)
        acc[m][n] = __builtin_amdgcn_mfma_f32_16x16x32_f16(af[m], bf[n],
                                                           acc[m][n], 0, 0, 0);
    __syncthreads();
  }

  float* Cz = C + (size_t)blockIdx.z * NCH * NG;
  const int crow = wr * 64 + ((lane >> 4) << 2);
  const int ccol = n0 + wc * 64 + fr;
#pragma unroll
  for (int m = 0; m < 4; ++m)
#pragma unroll
    for (int n = 0; n < 4; ++n) {
      const int col = ccol + n * 16;
#pragma unroll
      for (int r = 0; r < 4; ++r)
        Cz[(size_t)(crow + m * 16 + r) * NG + col] = acc[m][n][r];
    }
}

#define BARX __builtin_amdgcn_s_barrier()
#define PR1 __builtin_amdgcn_s_setprio(1)
#define PR0 __builtin_amdgcn_s_setprio(0)

// ---------------- GEMM1: 128x192 tile, BK=64 double-buffer (R17 proven) ----
__global__ __launch_bounds__(256, 2)
void gemm1_k64(const _Float16* __restrict__ A, const _Float16* __restrict__ B,
               const float* __restrict__ part, _Float16* __restrict__ igb,
               float* __restrict__ out0, _Float16* __restrict__ th) {
  constexpr int KS = 2048;
  constexpr int NT = 32;               // K-tiles of 64
  __shared__ __align__(16) _Float16 sA[2][128 * 64];
  __shared__ __align__(16) _Float16 sB[2][192 * 64];

  const int tid = threadIdx.x;
  const int l = tid & 63;
  const int wid = tid >> 6;
  const int wr = wid >> 1;             // M half (64 rows)
  const int wc = wid & 1;              // N half (96 cols)

  // bijective XCD swizzle: 512 blocks = 8 XCD x 4 M-tiles x 16 N-tiles
  const int bid = blockIdx.x;
  const int xcd = bid & 7;
  const int q = bid >> 3;
  const int by = xcd * 4 + q / 16;
  const int bx = q % 16;
  const int m0 = by * 128;
  const int n0 = bx * 192;

  // staging: thread -> rows rB+32j, chunk cB; source chunk pre-XORed
  const int rB = tid >> 3;             // 0..31
  const int cB = tid & 7;
  const int csw = (cB ^ (rB & 7)) << 3;      // halfs
  const _Float16* gA0 = A + (size_t)(m0 + rB) * KS + csw;
  const _Float16* gB0 = B + (size_t)(n0 + rB) * KS + csw;
  const int dsto = rB * 64 + cB * 8;

#define STG(bb, kt) do {                                               \
    const int kk_ = (kt) * 64;                                         \
    _Pragma("unroll")                                                  \
    for (int j = 0; j < 4; ++j)                                        \
      gload_lds16(gA0 + (size_t)(32 * j) * KS + kk_,                   \
                  (_Float16*)&sA[bb][dsto + j * 2048]);                \
    _Pragma("unroll")                                                  \
    for (int j = 0; j < 6; ++j)                                        \
      gload_lds16(gB0 + (size_t)(32 * j) * KS + kk_,                   \
                  (_Float16*)&sB[bb][dsto + j * 2048]);                \
  } while (0)

  const int fr = l & 15;
  const int kq = l >> 4;               // 0..3 : k-chunk within 32-half

#define RDA(dst, M, H, bb) do {                                        \
    const int row_ = wr * 64 + (M) * 16 + fr;                          \
    dst = *(const half8_t*)&sA[bb][row_ * 64 +                         \
          ((((H) * 4 + kq) ^ (row_ & 7)) << 3)];                       \
  } while (0)
#define RDB(dst, N_, H, bb) do {                                       \
    const int row_ = wc * 96 + (N_) * 16 + fr;                         \
    dst = *(const half8_t*)&sB[bb][row_ * 64 +                         \
          ((((H) * 4 + kq) ^ (row_ & 7)) << 3)];                       \
  } while (0)

  f32x4_t acc[4][6] = {};

#define BODY(t, bb) do {                                               \
    const int nt_ = ((t) + 1 < NT) ? (t) + 1 : NT - 1;                 \
    STG((bb) ^ 1, nt_);                                                \
    half8_t af[4][2], bf[6][2];                                        \
    _Pragma("unroll")                                                  \
    for (int m = 0; m < 4; ++m) {                                      \
      RDA(af[m][0], m, 0, bb); RDA(af[m][1], m, 1, bb);                \
    }                                                                  \
    _Pragma("unroll")                                                  \
    for (int n = 0; n < 6; ++n) {                                      \
      RDB(bf[n][0], n, 0, bb); RDB(bf[n][1], n, 1, bb);                \
    }                                                                  \
    PR1;                                                               \
    _Pragma("unroll")                                                  \
    for (int m = 0; m < 4; ++m)                                        \
      _Pragma("unroll")                                                \
      for (int n = 0; n < 6; ++n) {                                    \
        acc[m][n] = __builtin_amdgcn_mfma_f32_16x16x32_f16(            \
            af[m][0], bf[n][0], acc[m][n], 0, 0, 0);                   \
        acc[m][n] = __builtin_amdgcn_mfma_f32_16x16x32_f16(            \
            af[m][1], bf[n][1], acc[m][n], 0, 0, 0);                   \
      }                                                                \
    PR0;                                                               \
    asm volatile("s_waitcnt vmcnt(0)" ::: "memory");                   \
    BARX;                                                              \
  } while (0)

  STG(0, 0);
  asm volatile("s_waitcnt vmcnt(0)" ::: "memory");
  BARX;

#pragma unroll 1
  for (int t2 = 0; t2 < NT / 2; ++t2) {
    BODY(2 * t2,     0);
    BODY(2 * t2 + 1, 1);
  }

  // ---- epilogue: gate activations ----
  const int crow = m0 + wr * 64 + ((l >> 4) << 2);
  const int ccol = n0 + wc * 96 + fr;

  float pv[2][6];
  const int cbase = crow >> 5;   // lane-uniform per 64-row wave span
#pragma unroll
  for (int h = 0; h < 2; ++h)
#pragma unroll
    for (int n = 0; n < 6; ++n)
      pv[h][n] = part[(size_t)(cbase + h) * NG + ccol + n * 16];

#pragma unroll
  for (int m = 0; m < 4; ++m)
#pragma unroll
    for (int n = 0; n < 6; ++n) {
      const int col = ccol + n * 16;
#pragma unroll
      for (int r = 0; r < 4; ++r) {
        const int row = crow + m * 16 + r;
        float g = acc[m][n][r] + pv[m >> 1][n];
        if (col < 1024)
          igb[(size_t)row * HD + col] = (_Float16)sigmoidf_(g);
        else if (col < 2048)
          out0[(size_t)row * HD + (col - 1024)] = sigmoidf_(g);
        else
          th[(size_t)row * HD + (col - 2048)] = (_Float16)tanhf_(g);
      }
    }
#undef STG
#undef RDA
#undef RDB
#undef BODY
}

// ---------------- GEMM2: 128x64 tile, BK=64 double-buffer ------------------
// hr = (tanh(h) @ W2^T + b2) * ig ; K=1024 -> NT=16 bodies (was 32 events).
// Wave tile 64x32, acc[4][2]; dbuf LDS 48KB; grid 512 = 2 blocks/CU.
__global__ __launch_bounds__(256, 2)
void gemm2_k64(const _Float16* __restrict__ A, const _Float16* __restrict__ B,
               float* __restrict__ outf,
               const float* __restrict__ bias, const _Float16* __restrict__ mulh) {
  constexpr int KS = 1024;
  constexpr int NT = 16;               // K-tiles of 64
  __shared__ __align__(16) _Float16 sA[2][128 * 64];
  __shared__ __align__(16) _Float16 sB[2][64 * 64];

  const int tid = threadIdx.x;
  const int l = tid & 63;
  const int wid = tid >> 6;
  const int wr = wid >> 1;             // M half (64 rows)
  const int wc = wid & 1;              // N half (32 cols)

  // bijective XCD swizzle: 512 blocks = 8 XCD x 4 M-tiles x 16 N-tiles
  const int bid = blockIdx.x;
  const int xcd = bid & 7;
  const int q = bid >> 3;
  const int by = xcd * 4 + q / 16;
  const int bx = q % 16;
  const int m0 = by * 128;
  const int n0 = bx * 64;

  const int rB = tid >> 3;             // 0..31
  const int cB = tid & 7;
  const int csw = (cB ^ (rB & 7)) << 3;
  const _Float16* gA0 = A + (size_t)(m0 + rB) * KS + csw;
  const _Float16* gB0 = B + (size_t)(n0 + rB) * KS + csw;
  const int dsto = rB * 64 + cB * 8;

#define STG(bb, kt) do {                                               \
    const int kk_ = (kt) * 64;                                         \
    _Pragma("unroll")                                                  \
    for (int j = 0; j < 4; ++j)                                        \
      gload_lds16(gA0 + (size_t)(32 * j) * KS + kk_,                   \
                  (_Float16*)&sA[bb][dsto + j * 2048]);                \
    _Pragma("unroll")                                                  \
    for (int j = 0; j < 2; ++j)                                        \
      gload_lds16(gB0 + (size_t)(32 * j) * KS + kk_,                   \
                  (_Float16*)&sB[bb][dsto + j * 2048]);                \
  } while (0)

  const int fr = l & 15;
  const int kq = l >> 4;

#define RDA(dst, M, H, bb) do {                                        \
    const int row_ = wr * 64 + (M) * 16 + fr;                          \
    dst = *(const half8_t*)&sA[bb][row_ * 64 +                         \
          ((((H) * 4 + kq) ^ (row_ & 7)) << 3)];                       \
  } while (0)
#define RDB(dst, N_, H, bb) do {                                       \
    const int row_ = wc * 32 + (N_) * 16 + fr;                         \
    dst = *(const half8_t*)&sB[bb][row_ * 64 +                         \
          ((((H) * 4 + kq) ^ (row_ & 7)) << 3)];                       \
  } while (0)

  f32x4_t acc[4][2] = {};

#define BODY(t, bb) do {                                               \
    const int nt_ = ((t) + 1 < NT) ? (t) + 1 : NT - 1;                 \
    STG((bb) ^ 1, nt_);                                                \
    half8_t af[4][2], bf[2][2];                                        \
    _Pragma("unroll")                                                  \
    for (int m = 0; m < 4; ++m) {                                      \
      RDA(af[m][0], m, 0, bb); RDA(af[m][1], m, 1, bb);                \
    }                                                                  \
    _Pragma("unroll")                                                  \
    for (int n = 0; n < 2; ++n) {                                      \
      RDB(bf[n][0], n, 0, bb); RDB(bf[n][1], n, 1, bb);                \
    }                                                                  \
    PR1;                                                               \
    _Pragma("unroll")                                                  \
    for (int m = 0; m < 4; ++m)                                        \
      _Pragma("unroll")                                                \
      for (int n = 0; n < 2; ++n) {                                    \
        acc[m][n] = __builtin_amdgcn_mfma_f32_16x16x32_f16(            \
            af[m][0], bf[n][0], acc[m][n], 0, 0, 0);                   \
        acc[m][n] = __builtin_amdgcn_mfma_f32_16x16x32_f16(            \
            af[m][1], bf[n][1], acc[m][n], 0, 0, 0);                   \
      }                                                                \
    PR0;                                                               \
    asm volatile("s_waitcnt vmcnt(0)" ::: "memory");                   \
    BARX;                                                              \
  } while (0)

  STG(0, 0);
  asm volatile("s_waitcnt vmcnt(0)" ::: "memory");
  BARX;

#pragma unroll 1
  for (int t2 = 0; t2 < NT / 2; ++t2) {
    BODY(2 * t2,     0);
    BODY(2 * t2 + 1, 1);
  }

  // ---- epilogue ----
  const int crow = m0 + wr * 64 + ((l >> 4) << 2);
  const int ccol = n0 + wc * 32 + fr;
#pragma unroll
  for (int m = 0; m < 4; ++m)
#pragma unroll
    for (int n = 0; n < 2; ++n) {
      const int col = ccol + n * 16;
#pragma unroll
      for (int r = 0; r < 4; ++r) {
        const int row = crow + m * 16 + r;
        size_t idx = (size_t)row * HD + col;
        outf[idx] = (acc[m][n][r] + bias[col]) * (float)mulh[idx];
      }
    }
#undef STG
#undef RDA
#undef RDB
#undef BODY
}

// ---------------- launch ----------------
extern "C" void kernel_launch(void* const* d_in, const int* in_sizes, int n_in,
                              void* d_out, int out_size, void* d_ws, size_t ws_size,
                              hipStream_t stream) {
  const float* x  = (const float*)d_in[0];
  const float* W1 = (const float*)d_in[1];
  const float* b1 = (const float*)d_in[2];
  const float* W2 = (const float*)d_in[3];
  const float* b2 = (const float*)d_in[4];
  float* out0 = (float*)d_out;                          // fg [4096][1024]
  float* out1 = out0 + (size_t)S_SEQ * HD;              // hr [4096][1024]

  char* ws = (char*)d_ws;
  _Float16* Ah    = (_Float16*)(ws);                        // 16 MiB [4096][2048]
  _Float16* w1h   = (_Float16*)(ws + ((size_t)16 << 20));   // 12 MiB [3072][2048]
  _Float16* w2h   = (_Float16*)(ws + ((size_t)28 << 20));   //  2 MiB [1024][1024]
  _Float16* xsumh = (_Float16*)(ws + ((size_t)30 << 20));   // .25MiB [128][1024]
  float*    praw  = (float*)   (ws + ((size_t)31 << 20));   //  6 MiB [4][128][3072]
  float*    pout  = (float*)   (ws + ((size_t)37 << 20));   // 1.5MiB [128][3072]
  _Float16* igb   = (_Float16*)(ws + ((size_t)39 << 20));   //  8 MiB [4096][1024]
  _Float16* th    = (_Float16*)(ws + ((size_t)47 << 20));   //  8 MiB [4096][1024]

  prep<<<dim3(SCAN_BLOCKS + CONV_BLOCKS), dim3(256), 0, stream>>>(
      W1, W2, w1h, w2h, x, Ah, xsumh);

  gemm_part<<<dim3(NG / 128, 1, NZ), dim3(256), 0, stream>>>(
      xsumh, w1h + 1024, praw);

  scan_part<<<dim3(NG / 256), dim3(256), 0, stream>>>(praw, b1, pout);

  // GEMM1: 128x192, BK=64 dbuf, 512 blocks = 2/CU, XCD-swizzled
  gemm1_k64<<<dim3(512), dim3(256), 0, stream>>>(
      Ah, w1h, pout, igb, out0, th);

  // GEMM2: 128x64, BK=64 dbuf, 512 blocks = 2/CU, XCD-swizzled
  gemm2_k64<<<dim3(512), dim3(256), 0, stream>>>(
      th, w2h, out1, b2, igb);
}